// Round 5
// baseline (11821.876 us; speedup 1.0000x reference)
//
#include <hip/hip_runtime.h>
#include <hip/hip_bf16.h>
#include <stdint.h>
#include <stddef.h>

#define B_SZ   4096
#define U_SZ   1024
#define SEQ    5
#define TSTEPS 200
#define STEPS  204          // 5 warmup + 199 decode LSTM steps
#define NP     16           // p-blocks per G group
#define NG     32           // G groups

typedef __bf16 bf16_t;
typedef __bf16 bf16x8 __attribute__((ext_vector_type(8)));
typedef float  f32x4  __attribute__((ext_vector_type(4)));

#define AS1 __attribute__((address_space(1)))
#define AS3 __attribute__((address_space(3)))

// cached staging load (B panels / Rp: immutable)
#define LOAD_LDS16(gp, lp) \
    __builtin_amdgcn_global_load_lds((const AS1 unsigned int*)(gp), \
                                     (AS3 unsigned int*)(lp), 16, 0, 0)
// L1-bypass, L2-hit load (h within one XCD: writer's plain stores land in L2)
#define LOAD_LDS16_SC0(gp, lp) \
    __builtin_amdgcn_global_load_lds((const AS1 unsigned int*)(gp), \
                                     (AS3 unsigned int*)(lp), 16, 0, 1)
// fully-coherent load (h across XCDs): miss L1/L2, read the MALL
#define LOAD_LDS16_COH(gp, lp) \
    __builtin_amdgcn_global_load_lds((const AS1 unsigned int*)(gp), \
                                     (AS3 unsigned int*)(lp), 16, 0, 17)

__device__ __forceinline__ void store_h_coherent(bf16_t* p, unsigned int v) {
    asm volatile("global_store_short %0, %1, off sc0 sc1"
                 :: "v"(p), "v"(v) : "memory");
}

__device__ __forceinline__ float fsig(float x) {
    return 1.0f / (1.0f + __expf(-x));
}
__device__ __forceinline__ float ftanh(float x) {
    x = fminf(fmaxf(x, -15.0f), 15.0f);
    float e = __expf(2.0f * x);
    return (e - 1.0f) / (e + 1.0f);
}

// ---------------------------------------------------------------------------
// Pack R (1024 x 4096 fp32 row-major) into bf16 panels (unchanged, proven).
// ---------------------------------------------------------------------------
__global__ void pack_R(const float* __restrict__ R, bf16_t* __restrict__ Rp) {
    int idx = blockIdx.x * 256 + threadIdx.x;   // 4,194,304 total
    int e    = idx & 7;
    int slot = (idx >> 3) & 7;
    int c    = (idx >> 6) & 127;
    int kb   = (idx >> 13) & 15;
    int ub   = idx >> 17;
    int g  = (c >> 4) & 3;
    int wc = c >> 6;
    int cl = c & 15;
    int n  = g * 1024 + ub * 32 + wc * 16 + cl;
    int k  = kb * 64 + ((slot ^ (c & 7)) << 3) + e;
    Rp[idx] = (bf16_t)R[(size_t)k * 4096 + n];
}

// ===========================================================================
// PATH A: persistent cooperative kernel, XCD-pinned G groups, PIPELINED
// K-loop: lsB double-buffered (B panels issued a full phase ahead of use,
// hiding MALL latency); c(T=0) in global fp32 (block-private, L2-local);
// x in registers + __shfl.  LDS = 16 KB lsA + 64 KB lsB = exactly 80 KB.
// ===========================================================================
__global__ __launch_bounds__(256, 2)
void lstm_persist(bf16_t* __restrict__ h0,
                  bf16_t* __restrict__ h1,
                  const bf16_t* __restrict__ Rp,
                  const float* __restrict__ Wx,     // (4096,)
                  const float* __restrict__ bias,   // (4096,)
                  const float* __restrict__ w1,     // (1024,)
                  const float* __restrict__ b1,
                  const float* __restrict__ w2,
                  const float* __restrict__ b2,
                  const float* __restrict__ inputs, // [4096,5]
                  float* __restrict__ praw,         // 3*4096
                  float* __restrict__ out,          // [4096,200]
                  float* __restrict__ cst,          // c state (fp32, 16 MB)
                  unsigned int* __restrict__ bar)   // ctrs + xcd table
{
    __shared__ __align__(16) bf16_t lsA[128 * 64];       // 16 KB
    __shared__ __align__(16) bf16_t lsB[2][2][8192];     // 64 KB (dbuf x 2 T)

    const int tid  = threadIdx.x;
    const int wave = tid >> 6;
    const int lane = tid & 63;
    const int bid  = blockIdx.x;            // 0..511
    const int G    = (bid & 7) * 4 + ((bid >> 3) & 3);   // same-G => same bid%8
    const int p    = bid >> 5;              // 0..15
    const int l15  = lane & 15;
    const int quad = lane >> 4;
    const int rbase = (wave >> 1) * 64;
    const int wc    = wave & 1;
    const int a_kk  = (((lane & 7) ^ (lane >> 3)) << 3);

    const bf16_t* Bp0 = Rp + (size_t)(2 * p) * 131072;
    const bf16_t* Bp1 = Bp0 + 131072;

    const int uuA[2] = { (2 * p) * 32 + wc * 16 + l15,
                         (2 * p) * 32 + wc * 16 + l15 + 32 };

    const float b1s = b1[0], w2s = w2[0], b2s = b2[0];

    // ---- init: publish my XCD, grid barrier, per-G same-XCD check ----
    {
        unsigned int myxcc = 0;
        asm volatile("s_getreg_b32 %0, hwreg(20, 0, 32)" : "=s"(myxcc));
        unsigned int* xcdtab = bar + 1024;
        unsigned int* gbar   = bar + 2048;
        if (tid == 0) {
            __hip_atomic_store(&xcdtab[G * 16 + p], myxcc | 0x100u,
                               __ATOMIC_RELAXED, __HIP_MEMORY_SCOPE_AGENT);
            asm volatile("s_waitcnt vmcnt(0)" ::: "memory");
            __hip_atomic_fetch_add(gbar, 1u, __ATOMIC_RELAXED,
                                   __HIP_MEMORY_SCOPE_AGENT);
            while (__hip_atomic_load(gbar, __ATOMIC_RELAXED,
                                     __HIP_MEMORY_SCOPE_AGENT) < (unsigned)(NP * NG))
                __builtin_amdgcn_s_sleep(2);
            unsigned int x0 = __hip_atomic_load(&xcdtab[G * 16 + 0],
                                                __ATOMIC_RELAXED,
                                                __HIP_MEMORY_SCOPE_AGENT);
            int ok = 1;
            for (int i = 1; i < 16; ++i)
                ok &= (__hip_atomic_load(&xcdtab[G * 16 + i], __ATOMIC_RELAXED,
                                         __HIP_MEMORY_SCOPE_AGENT) == x0);
            ((short*)lsA)[0] = (short)ok;     // flag through lsA (pre-staging)
        }
    }
    __syncthreads();
    const bool fastp = (((volatile short*)lsA)[0] != 0);
    __syncthreads();

    float c1[4][4] = {};                     // c, T=1 half (registers)

    #pragma clang loop unroll(disable)
    for (int t = 0; t < STEPS; ++t) {
        const bf16_t* hin  = (t & 1) ? h1 : h0;
        bf16_t*       hout = (t & 1) ? h0 : h1;
        float*       pr_acc  = praw + (size_t)(t % 3) * B_SZ;
        const float* pr_read = praw + (size_t)((t + 2) % 3) * B_SZ;
        float*       pr_zero = praw + (size_t)((t + 1) % 3) * B_SZ;
        const bf16_t* Ap = hin + (size_t)G * 128 * U_SZ;

        // ---- stage head for kb=0 (A0 + both panels) ----
        if (fastp) {
            #pragma unroll
            for (int i = 0; i < 4; ++i) {
                int chunk = wave * 4 + i;
                int m  = chunk * 8 + (lane >> 3);
                LOAD_LDS16_SC0(Ap + (size_t)m * U_SZ + a_kk, &lsA[chunk * 512]);
            }
        } else {
            #pragma unroll
            for (int i = 0; i < 4; ++i) {
                int chunk = wave * 4 + i;
                int m  = chunk * 8 + (lane >> 3);
                LOAD_LDS16_COH(Ap + (size_t)m * U_SZ + a_kk, &lsA[chunk * 512]);
            }
        }
        #pragma unroll
        for (int i = 0; i < 4; ++i) {
            int chunk = wave * 4 + i;
            LOAD_LDS16(Bp0 + chunk * 512 + lane * 8, &lsB[0][0][chunk * 512]);
            LOAD_LDS16(Bp1 + chunk * 512 + lane * 8, &lsB[0][1][chunk * 512]);
        }

        // ---- prologue: x for row (rbase+lane), in-register (overlaps stage) --
        float xw;
        {
            int row = G * 128 + rbase + lane;
            float x;
            if (t < SEQ) {
                x = inputs[row * SEQ + t];
            } else {
                float pv = __hip_atomic_load(&pr_read[row], __ATOMIC_RELAXED,
                                             __HIP_MEMORY_SCOPE_AGENT);
                float x1 = fmaxf(pv + b1s, 0.f);
                x = (t == SEQ) ? x1 : x1 * w2s + b2s;
                if (p == 0 && (wave & 1) == 0)
                    out[(size_t)row * TSTEPS + (t - SEQ)] = x;
            }
            xw = x;
            if (p == 0 && (wave & 1) == 0)
                __hip_atomic_store(&pr_zero[row], 0.f, __ATOMIC_RELAXED,
                                   __HIP_MEMORY_SCOPE_AGENT);
        }

        // ---- pipelined K-loop ----
        f32x4 acc[2][4][4] = {};

        for (int kb = 0; kb < 16; ++kb) {
            __syncthreads();          // drains exactly A_kb + P_kb (needed now)

            if (kb < 15) {            // issue next panels into other parity:
                const int kn = kb + 1;//   full compute phase covers MALL latency
                #pragma unroll
                for (int i = 0; i < 4; ++i) {
                    int chunk = wave * 4 + i;
                    LOAD_LDS16(Bp0 + (size_t)kn * 8192 + chunk * 512 + lane * 8,
                               &lsB[kn & 1][0][chunk * 512]);
                    LOAD_LDS16(Bp1 + (size_t)kn * 8192 + chunk * 512 + lane * 8,
                               &lsB[kn & 1][1][chunk * 512]);
                }
            }

            const bf16_t* lb = &lsB[kb & 1][0][0];
            __builtin_amdgcn_s_setprio(1);
            #pragma unroll
            for (int kh = 0; kh < 2; ++kh) {
                int sw = (((kh * 4 + quad) ^ (lane & 7)) << 3);
                bf16x8 af[4];
                #pragma unroll
                for (int mi = 0; mi < 4; ++mi)
                    af[mi] = *(const bf16x8*)&lsA[(rbase + mi * 16 + l15) * 64 + sw];
                #pragma unroll
                for (int T = 0; T < 2; ++T) {
                    bf16x8 bfr[4];
                    #pragma unroll
                    for (int ni = 0; ni < 4; ++ni)
                        bfr[ni] = *(const bf16x8*)
                            &lb[T * 8192 + (wc * 64 + ni * 16 + l15) * 64 + sw];
                    #pragma unroll
                    for (int mi = 0; mi < 4; ++mi)
                        #pragma unroll
                        for (int ni = 0; ni < 4; ++ni)
                            acc[T][mi][ni] = __builtin_amdgcn_mfma_f32_16x16x32_bf16(
                                af[mi], bfr[ni], acc[T][mi][ni], 0, 0, 0);
                }
            }
            __builtin_amdgcn_s_setprio(0);

            __builtin_amdgcn_s_barrier();   // raw: reads done, NO drain

            if (kb < 15) {                  // re-stage single-buffered A
                const int kn = kb + 1;
                if (fastp) {
                    #pragma unroll
                    for (int i = 0; i < 4; ++i) {
                        int chunk = wave * 4 + i;
                        int m  = chunk * 8 + (lane >> 3);
                        LOAD_LDS16_SC0(Ap + (size_t)m * U_SZ + kn * 64 + a_kk,
                                       &lsA[chunk * 512]);
                    }
                } else {
                    #pragma unroll
                    for (int i = 0; i < 4; ++i) {
                        int chunk = wave * 4 + i;
                        int m  = chunk * 8 + (lane >> 3);
                        LOAD_LDS16_COH(Ap + (size_t)m * U_SZ + kn * 64 + a_kk,
                                       &lsA[chunk * 512]);
                    }
                }
            }
        }

        // ---- epilogue: gates, c RMW (global, L2-local), h store, pred ----
        float g_b[2][4], g_w[2][4], w1u[2];
        #pragma unroll
        for (int T = 0; T < 2; ++T) {
            #pragma unroll
            for (int g = 0; g < 4; ++g) {
                g_b[T][g] = bias[g * 1024 + uuA[T]];
                g_w[T][g] = Wx[g * 1024 + uuA[T]];
            }
            w1u[T] = w1[uuA[T]];
        }
        const bool do_pred = (t >= SEQ - 1);
        const bool do_h    = (t + 1 < STEPS);

        #pragma unroll
        for (int mi = 0; mi < 4; ++mi) {
            #pragma unroll
            for (int r = 0; r < 4; ++r) {
                int rl   = rbase + mi * 16 + quad * 4 + r;
                int brow = G * 128 + rl;
                float xv = __shfl(xw, mi * 16 + quad * 4 + r);
                float ps = 0.f;
                #pragma unroll
                for (int T = 0; T < 2; ++T) {
                    float zi = acc[T][mi][0][r] + g_b[T][0] + xv * g_w[T][0];
                    float zf = acc[T][mi][1][r] + g_b[T][1] + xv * g_w[T][1];
                    float zg = acc[T][mi][2][r] + g_b[T][2] + xv * g_w[T][2];
                    float zo = acc[T][mi][3][r] + g_b[T][3] + xv * g_w[T][3];
                    float ig = fsig(zi), fg = fsig(zf);
                    float gg = ftanh(zg), og = fsig(zo);
                    size_t off = (size_t)brow * U_SZ + uuA[T];
                    float c_old = (T == 0) ? cst[off] : c1[mi][r];
                    float cn = fg * c_old + ig * gg;
                    if (T == 0) cst[off] = cn; else c1[mi][r] = cn;
                    float hv = og * ftanh(cn);
                    if (do_h) {
                        unsigned short hb =
                            __builtin_bit_cast(unsigned short, (bf16_t)hv);
                        if (fastp) ((unsigned short*)hout)[off] = hb;
                        else       store_h_coherent(hout + off, (unsigned int)hb);
                    }
                    ps += hv * w1u[T];
                }
                if (do_pred) {
                    ps += __shfl_xor(ps, 1);
                    ps += __shfl_xor(ps, 2);
                    ps += __shfl_xor(ps, 4);
                    ps += __shfl_xor(ps, 8);
                    if (l15 == 0) atomicAdd(&pr_acc[brow], ps);
                }
            }
        }

        // ---- per-G inter-block barrier (16 blocks) ----
        __syncthreads();   // drains h/c/pr stores (vmcnt(0))
        if (tid == 0) {
            unsigned int* c0 = &bar[G << 5];       // 128B-padded counter
            __hip_atomic_fetch_add(c0, 1u, __ATOMIC_RELAXED,
                                   __HIP_MEMORY_SCOPE_AGENT);
            const unsigned tgt = (unsigned)(NP * (t + 1));
            while (__hip_atomic_load(c0, __ATOMIC_RELAXED,
                                     __HIP_MEMORY_SCOPE_AGENT) < tgt)
                __builtin_amdgcn_s_sleep(4);
        }
        __syncthreads();
    }

    // ---- final output slot 199 from praw of step 203 (203 % 3 == 2) ----
    if (p == 0 && tid < 128) {
        int row = G * 128 + tid;
        float pv = __hip_atomic_load(&praw[2 * B_SZ + row], __ATOMIC_RELAXED,
                                     __HIP_MEMORY_SCOPE_AGENT);
        float x1 = fmaxf(pv + b1s, 0.f);
        out[(size_t)row * TSTEPS + 199] = x1 * w2s + b2s;
    }
}

// ===========================================================================
// PATH B (fallback, verbatim round-0 proven kernels): one launch per step.
// ===========================================================================
__global__ __launch_bounds__(256, 2)
void lstm_step(const bf16_t* __restrict__ hin,
               bf16_t* __restrict__ hout,
               float* __restrict__ cst,
               const bf16_t* __restrict__ Rp,
               const float* __restrict__ Wx,
               const float* __restrict__ bias,
               const float* __restrict__ w1,
               const float* __restrict__ b1,
               const float* __restrict__ w2,
               const float* __restrict__ b2,
               const float* __restrict__ inputs,
               float* __restrict__ praw,
               float* __restrict__ out,
               int t)
{
    __shared__ __align__(16) bf16_t lsA[128 * 64];
    __shared__ __align__(16) bf16_t lsB[2][128 * 64];
    __shared__ float lsX[128];

    const int tid  = threadIdx.x;
    const int wave = tid >> 6;
    const int lane = tid & 63;
    const int p    = blockIdx.x;
    const int G    = blockIdx.y;
    const int l15  = lane & 15;
    const int quad = lane >> 4;
    const int rbase = (wave >> 1) * 64;
    const int wc    = wave & 1;

    float*       pr_acc  = praw + (size_t)(t % 3) * B_SZ;
    const float* pr_read = praw + (size_t)((t + 2) % 3) * B_SZ;
    float*       pr_zero = praw + (size_t)((t + 1) % 3) * B_SZ;

    if (tid < 128) {
        int row = G * 128 + tid;
        float x;
        if (t < SEQ) {
            x = inputs[row * SEQ + t];
        } else {
            float x1 = fmaxf(pr_read[row] + b1[0], 0.f);
            x = (t == SEQ) ? x1 : x1 * w2[0] + b2[0];
            if (p == 0) out[(size_t)row * TSTEPS + (t - SEQ)] = x;
        }
        lsX[tid] = x;
        if (p == 0) pr_zero[row] = 0.f;
    }

    f32x4 acc[2][4][4] = {};
    const bf16_t* Ap  = hin + (size_t)G * 128 * U_SZ;
    const bf16_t* Bp0 = Rp + (size_t)(2 * p) * 131072;
    const bf16_t* Bp1 = Bp0 + 131072;
    const int a_kk = (((lane & 7) ^ (lane >> 3)) << 3);

    for (int kb = 0; kb < 16; ++kb) {
        #pragma unroll
        for (int i = 0; i < 4; ++i) {
            int chunk = wave * 4 + i;
            int m  = chunk * 8 + (lane >> 3);
            LOAD_LDS16(Ap + (size_t)m * U_SZ + kb * 64 + a_kk, &lsA[chunk * 512]);
        }
        #pragma unroll
        for (int i = 0; i < 4; ++i) {
            int chunk = wave * 4 + i;
            LOAD_LDS16(Bp0 + (size_t)kb * 8192 + chunk * 512 + lane * 8,
                       &lsB[0][chunk * 512]);
            LOAD_LDS16(Bp1 + (size_t)kb * 8192 + chunk * 512 + lane * 8,
                       &lsB[1][chunk * 512]);
        }
        __syncthreads();

        #pragma unroll
        for (int kh = 0; kh < 2; ++kh) {
            int sw = (((kh * 4 + quad) ^ (lane & 7)) << 3);
            bf16x8 af[4];
            #pragma unroll
            for (int mi = 0; mi < 4; ++mi)
                af[mi] = *(const bf16x8*)&lsA[(rbase + mi * 16 + l15) * 64 + sw];
            #pragma unroll
            for (int T = 0; T < 2; ++T) {
                bf16x8 bfr[4];
                #pragma unroll
                for (int ni = 0; ni < 4; ++ni)
                    bfr[ni] = *(const bf16x8*)
                        &lsB[T][(wc * 64 + ni * 16 + l15) * 64 + sw];
                #pragma unroll
                for (int mi = 0; mi < 4; ++mi)
                    #pragma unroll
                    for (int ni = 0; ni < 4; ++ni)
                        acc[T][mi][ni] = __builtin_amdgcn_mfma_f32_16x16x32_bf16(
                            af[mi], bfr[ni], acc[T][mi][ni], 0, 0, 0);
            }
        }
        __syncthreads();
    }

    int uu[2];
    uu[0] = (2 * p) * 32 + wc * 16 + l15;
    uu[1] = uu[0] + 32;
    float g_b[2][4], g_w[2][4], w1u[2];
    #pragma unroll
    for (int T = 0; T < 2; ++T) {
        #pragma unroll
        for (int g = 0; g < 4; ++g) {
            g_b[T][g] = bias[g * 1024 + uu[T]];
            g_w[T][g] = Wx[g * 1024 + uu[T]];
        }
        w1u[T] = w1[uu[T]];
    }
    const bool do_pred = (t >= SEQ - 1);

    #pragma unroll
    for (int mi = 0; mi < 4; ++mi) {
        #pragma unroll
        for (int r = 0; r < 4; ++r) {
            int rl   = rbase + mi * 16 + quad * 4 + r;
            int brow = G * 128 + rl;
            float xv = lsX[rl];
            float ps = 0.f;
            #pragma unroll
            for (int T = 0; T < 2; ++T) {
                float zi = acc[T][mi][0][r] + g_b[T][0] + xv * g_w[T][0];
                float zf = acc[T][mi][1][r] + g_b[T][1] + xv * g_w[T][1];
                float zg = acc[T][mi][2][r] + g_b[T][2] + xv * g_w[T][2];
                float zo = acc[T][mi][3][r] + g_b[T][3] + xv * g_w[T][3];
                float ig = fsig(zi), fg = fsig(zf);
                float gg = ftanh(zg), og = fsig(zo);
                size_t off = (size_t)brow * U_SZ + uu[T];
                float cn = fg * cst[off] + ig * gg;
                cst[off] = cn;
                float hv = og * ftanh(cn);
                hout[off] = (bf16_t)hv;
                ps += hv * w1u[T];
            }
            if (do_pred) {
                ps += __shfl_xor(ps, 1);
                ps += __shfl_xor(ps, 2);
                ps += __shfl_xor(ps, 4);
                ps += __shfl_xor(ps, 8);
                if (l15 == 0) atomicAdd(&pr_acc[brow], ps);
            }
        }
    }
}

__global__ void pred_final(const float* __restrict__ praw,
                           const float* __restrict__ b1,
                           const float* __restrict__ w2,
                           const float* __restrict__ b2,
                           float* __restrict__ out)
{
    int row = blockIdx.x * 256 + threadIdx.x;
    float x1 = fmaxf(praw[2 * B_SZ + row] + b1[0], 0.f);
    out[(size_t)row * TSTEPS + 199] = x1 * w2[0] + b2[0];
}

extern "C" void kernel_launch(void* const* d_in, const int* in_sizes, int n_in,
                              void* d_out, int out_size, void* d_ws, size_t ws_size,
                              hipStream_t stream) {
    const float* inputs = (const float*)d_in[0];   // [4096,5,1]
    const float* Wx     = (const float*)d_in[1];   // [1,4096]
    const float* R      = (const float*)d_in[2];   // [1024,4096]
    const float* bias   = (const float*)d_in[3];   // [4096]
    const float* w1     = (const float*)d_in[4];   // [1024,1]
    const float* b1     = (const float*)d_in[5];
    const float* w2     = (const float*)d_in[6];
    const float* b2     = (const float*)d_in[7];
    float* out = (float*)d_out;

    char* ws = (char*)d_ws;
    const size_t RP_BYTES  = (size_t)32 * 131072 * 2;          // 8 MB
    const size_t H_BYTES   = (size_t)B_SZ * U_SZ * 2;          // 8 MB
    const size_t C_BYTES   = (size_t)B_SZ * U_SZ * 4;          // 16 MB
    const size_t PR_BYTES  = (size_t)3 * B_SZ * 4;             // 48 KB
    const size_t BAR_BYTES = (size_t)16384;                    // ctrs + xcd tab
    bf16_t* Rp   = (bf16_t*)ws;                ws += RP_BYTES;
    bf16_t* h0   = (bf16_t*)ws;                ws += H_BYTES;
    bf16_t* h1   = (bf16_t*)ws;                ws += H_BYTES;
    float*  cbuf = (float*)ws;                 ws += C_BYTES;
    float*  praw = (float*)ws;                 ws += PR_BYTES;
    unsigned int* bar = (unsigned int*)ws;     ws += BAR_BYTES;
    bf16_t* hb[2] = {h0, h1};

    hipMemsetAsync(h0, 0, H_BYTES, stream);
    hipMemsetAsync(cbuf, 0, C_BYTES, stream);
    hipMemsetAsync(praw, 0, PR_BYTES, stream);
    hipMemsetAsync(bar, 0, BAR_BYTES, stream);

    pack_R<<<16384, 256, 0, stream>>>(R, Rp);

    void* args[14];
    args[0]  = (void*)&h0;
    args[1]  = (void*)&h1;
    args[2]  = (void*)&Rp;
    args[3]  = (void*)&Wx;
    args[4]  = (void*)&bias;
    args[5]  = (void*)&w1;
    args[6]  = (void*)&b1;
    args[7]  = (void*)&w2;
    args[8]  = (void*)&b2;
    args[9]  = (void*)&inputs;
    args[10] = (void*)&praw;
    args[11] = (void*)&out;
    args[12] = (void*)&cbuf;
    args[13] = (void*)&bar;

    hipError_t cerr = hipLaunchCooperativeKernel((const void*)lstm_persist,
                                                 dim3(NP * NG, 1, 1),
                                                 dim3(256, 1, 1),
                                                 args, 0, stream);
    if (cerr != hipSuccess) {
        (void)hipGetLastError();   // clear sticky error, take proven path
        dim3 grid(NP, NG);
        int cur = 0;
        for (int t = 0; t < STEPS; ++t) {
            lstm_step<<<grid, 256, 0, stream>>>(hb[cur], hb[1 - cur], cbuf, Rp,
                                                Wx, bias, w1, b1, w2, b2,
                                                inputs, praw, out, t);
            cur ^= 1;
        }
        pred_final<<<16, 256, 0, stream>>>(praw, b1, w2, b2, out);
    }
}

// Round 6
// 8638.004 us; speedup vs baseline: 1.3686x; 1.3686x over previous
//
#include <hip/hip_runtime.h>
#include <hip/hip_bf16.h>
#include <stdint.h>
#include <stddef.h>

#define B_SZ   4096
#define U_SZ   1024
#define SEQ    5
#define TSTEPS 200
#define STEPS  204          // 5 warmup + 199 decode LSTM steps

typedef __bf16 bf16_t;
typedef __bf16 bf16x8 __attribute__((ext_vector_type(8)));
typedef float  f32x4  __attribute__((ext_vector_type(4)));

#define AS1 __attribute__((address_space(1)))
#define AS3 __attribute__((address_space(3)))

#define LOAD_LDS16(gp, lp) \
    __builtin_amdgcn_global_load_lds((const AS1 unsigned int*)(gp), \
                                     (AS3 unsigned int*)(lp), 16, 0, 0)

__device__ __forceinline__ float fsig(float x) {
    return 1.0f / (1.0f + __expf(-x));
}
__device__ __forceinline__ float ftanh(float x) {
    x = fminf(fmaxf(x, -15.0f), 15.0f);
    float e = __expf(2.0f * x);
    return (e - 1.0f) / (e + 1.0f);
}

// ---------------------------------------------------------------------------
// Pack R (1024 x 4096 fp32 row-major) into bf16 panels, one per ub (32 u's),
// with XOR-swizzled 16B slots to kill LDS bank conflicts (unchanged, proven).
// ---------------------------------------------------------------------------
__global__ void pack_R(const float* __restrict__ R, bf16_t* __restrict__ Rp) {
    int idx = blockIdx.x * 256 + threadIdx.x;   // 4,194,304 total
    int e    = idx & 7;
    int slot = (idx >> 3) & 7;                  // physical 16B slot in row
    int c    = (idx >> 6) & 127;
    int kb   = (idx >> 13) & 15;
    int ub   = idx >> 17;
    int g  = (c >> 4) & 3;
    int wc = c >> 6;
    int cl = c & 15;
    int n  = g * 1024 + ub * 32 + wc * 16 + cl;
    int k  = kb * 64 + ((slot ^ (c & 7)) << 3) + e;   // un-swizzle -> logical k
    Rp[idx] = (bf16_t)R[(size_t)k * 4096 + n];
}

// ---------------------------------------------------------------------------
// One LSTM step (round-0 structure: per-step launch, p-pinned grid, c RMW in
// global) with a PIPELINED K-loop:
//   top __syncthreads drains A(kb)+B(kb)  [both latency-covered]
//   -> issue A(kb+1) into other lsA parity (covered by ds_read+MFMA phase)
//   -> ds_read ALL 24 fragments to regs
//   -> lgkmcnt(0) + raw s_barrier  (NO vm drain: A(kb+1) stays in flight)
//   -> issue B(kb+1) into lsB      (covered by MFMA cluster; B is L2-hit)
//   -> 64 MFMAs [setprio]
// LDS: lsA 2x16KB + lsB 32KB + lsX = 66KB -> still 2 blocks/CU.
// ---------------------------------------------------------------------------
__global__ __launch_bounds__(256, 2)
void lstm_step(const bf16_t* __restrict__ hin,
               bf16_t* __restrict__ hout,
               float* __restrict__ cst,
               const bf16_t* __restrict__ Rp,
               const float* __restrict__ Wx,     // (4096,)
               const float* __restrict__ bias,   // (4096,)
               const float* __restrict__ w1,     // (1024,)
               const float* __restrict__ b1,
               const float* __restrict__ w2,
               const float* __restrict__ b2,
               const float* __restrict__ inputs, // [4096,5]
               float* __restrict__ praw,         // 3*4096
               float* __restrict__ out,          // [4096,200]
               int t)
{
    __shared__ __align__(16) bf16_t lsA[2][8192];        // 32 KB (dbuf)
    __shared__ __align__(16) bf16_t lsB[2][8192];        // 32 KB
    __shared__ float lsX[128];

    const int tid  = threadIdx.x;
    const int wave = tid >> 6;
    const int lane = tid & 63;
    const int p    = blockIdx.x;   // 0..15 fastest -> panels pinned per XCD
    const int G    = blockIdx.y;   // 0..31
    const int l15  = lane & 15;
    const int quad = lane >> 4;
    const int rbase = (wave >> 1) * 64;
    const int wc    = wave & 1;
    const int a_kk  = (((lane & 7) ^ (lane >> 3)) << 3);

    float*       pr_acc  = praw + (size_t)(t % 3) * B_SZ;
    const float* pr_read = praw + (size_t)((t + 2) % 3) * B_SZ;
    float*       pr_zero = praw + (size_t)((t + 1) % 3) * B_SZ;

    const bf16_t* Ap  = hin + (size_t)G * 128 * U_SZ;
    const bf16_t* Bp0 = Rp + (size_t)(2 * p) * 131072;
    const bf16_t* Bp1 = Bp0 + 131072;

    // ---- prologue staging: A(0) -> lsA[0], B(0) -> lsB ----
    #pragma unroll
    for (int i = 0; i < 4; ++i) {
        int chunk = wave * 4 + i;
        int m  = chunk * 8 + (lane >> 3);
        LOAD_LDS16(Ap + (size_t)m * U_SZ + a_kk, &lsA[0][chunk * 512]);
    }
    #pragma unroll
    for (int i = 0; i < 4; ++i) {
        int chunk = wave * 4 + i;
        LOAD_LDS16(Bp0 + chunk * 512 + lane * 8, &lsB[0][chunk * 512]);
        LOAD_LDS16(Bp1 + chunk * 512 + lane * 8, &lsB[1][chunk * 512]);
    }

    // ---- prologue: x for my 128 rows (+ out write + praw-slot zero) ----
    if (tid < 128) {
        int row = G * 128 + tid;
        float x;
        if (t < SEQ) {
            x = inputs[row * SEQ + t];
        } else {
            float x1 = fmaxf(pr_read[row] + b1[0], 0.f);
            x = (t == SEQ) ? x1 : x1 * w2[0] + b2[0];
            if (p == 0) out[(size_t)row * TSTEPS + (t - SEQ)] = x;
        }
        lsX[tid] = x;
        if (p == 0) pr_zero[row] = 0.f;
    }

    // ---- pipelined K-loop ----
    f32x4 acc[2][4][4] = {};

    for (int kb = 0; kb < 16; ++kb) {
        __syncthreads();            // drains A(kb) + B(kb) (both covered)

        if (kb < 15) {              // A(kb+1) -> other parity, longest cover
            const int kn = kb + 1;
            #pragma unroll
            for (int i = 0; i < 4; ++i) {
                int chunk = wave * 4 + i;
                int m  = chunk * 8 + (lane >> 3);
                LOAD_LDS16(Ap + (size_t)m * U_SZ + kn * 64 + a_kk,
                           &lsA[kn & 1][chunk * 512]);
            }
        }

        // ds_read all fragments for kb into registers
        const bf16_t* la = &lsA[kb & 1][0];
        bf16x8 af[2][4], bfr[2][2][4];
        #pragma unroll
        for (int kh = 0; kh < 2; ++kh) {
            int sw = (((kh * 4 + quad) ^ (lane & 7)) << 3);
            #pragma unroll
            for (int mi = 0; mi < 4; ++mi)
                af[kh][mi] = *(const bf16x8*)&la[(rbase + mi * 16 + l15) * 64 + sw];
            #pragma unroll
            for (int T = 0; T < 2; ++T)
                #pragma unroll
                for (int ni = 0; ni < 4; ++ni)
                    bfr[kh][T][ni] = *(const bf16x8*)
                        &lsB[T][(wc * 64 + ni * 16 + l15) * 64 + sw];
        }

        // my LDS reads complete -> barrier (NO vm drain: A(kb+1) in flight)
        asm volatile("s_waitcnt lgkmcnt(0)" ::: "memory");
        __builtin_amdgcn_sched_barrier(0);
        __builtin_amdgcn_s_barrier();
        __builtin_amdgcn_sched_barrier(0);

        if (kb < 15) {              // B(kb+1): safe now, covered by MFMAs
            const int kn = kb + 1;
            #pragma unroll
            for (int i = 0; i < 4; ++i) {
                int chunk = wave * 4 + i;
                LOAD_LDS16(Bp0 + (size_t)kn * 8192 + chunk * 512 + lane * 8,
                           &lsB[0][chunk * 512]);
                LOAD_LDS16(Bp1 + (size_t)kn * 8192 + chunk * 512 + lane * 8,
                           &lsB[1][chunk * 512]);
            }
        }

        __builtin_amdgcn_s_setprio(1);
        #pragma unroll
        for (int kh = 0; kh < 2; ++kh)
            #pragma unroll
            for (int T = 0; T < 2; ++T)
                #pragma unroll
                for (int mi = 0; mi < 4; ++mi)
                    #pragma unroll
                    for (int ni = 0; ni < 4; ++ni)
                        acc[T][mi][ni] = __builtin_amdgcn_mfma_f32_16x16x32_bf16(
                            af[kh][mi], bfr[kh][T][ni], acc[T][mi][ni], 0, 0, 0);
        __builtin_amdgcn_s_setprio(0);
    }

    // ---- epilogue: gates, c RMW (global fp32), h write, pred partials ----
    int uu[2];
    uu[0] = (2 * p) * 32 + wc * 16 + l15;
    uu[1] = uu[0] + 32;
    float g_b[2][4], g_w[2][4], w1u[2];
    #pragma unroll
    for (int T = 0; T < 2; ++T) {
        #pragma unroll
        for (int g = 0; g < 4; ++g) {
            g_b[T][g] = bias[g * 1024 + uu[T]];
            g_w[T][g] = Wx[g * 1024 + uu[T]];
        }
        w1u[T] = w1[uu[T]];
    }
    const bool do_pred = (t >= SEQ - 1);

    #pragma unroll
    for (int mi = 0; mi < 4; ++mi) {
        #pragma unroll
        for (int r = 0; r < 4; ++r) {
            int rl   = rbase + mi * 16 + quad * 4 + r;
            int brow = G * 128 + rl;
            float xv = lsX[rl];
            float ps = 0.f;
            #pragma unroll
            for (int T = 0; T < 2; ++T) {
                float zi = acc[T][mi][0][r] + g_b[T][0] + xv * g_w[T][0];
                float zf = acc[T][mi][1][r] + g_b[T][1] + xv * g_w[T][1];
                float zg = acc[T][mi][2][r] + g_b[T][2] + xv * g_w[T][2];
                float zo = acc[T][mi][3][r] + g_b[T][3] + xv * g_w[T][3];
                float ig = fsig(zi), fg = fsig(zf);
                float gg = ftanh(zg), og = fsig(zo);
                size_t off = (size_t)brow * U_SZ + uu[T];
                float cn = fg * cst[off] + ig * gg;
                cst[off] = cn;
                float hv = og * ftanh(cn);
                hout[off] = (bf16_t)hv;
                ps += hv * w1u[T];
            }
            if (do_pred) {
                ps += __shfl_xor(ps, 1);
                ps += __shfl_xor(ps, 2);
                ps += __shfl_xor(ps, 4);
                ps += __shfl_xor(ps, 8);
                if (l15 == 0) atomicAdd(&pr_acc[brow], ps);
            }
        }
    }
}

// final output slot 199 from praw of step 203 (203 % 3 == 2)
__global__ void pred_final(const float* __restrict__ praw,
                           const float* __restrict__ b1,
                           const float* __restrict__ w2,
                           const float* __restrict__ b2,
                           float* __restrict__ out)
{
    int row = blockIdx.x * 256 + threadIdx.x;
    float x1 = fmaxf(praw[2 * B_SZ + row] + b1[0], 0.f);
    out[(size_t)row * TSTEPS + 199] = x1 * w2[0] + b2[0];
}

extern "C" void kernel_launch(void* const* d_in, const int* in_sizes, int n_in,
                              void* d_out, int out_size, void* d_ws, size_t ws_size,
                              hipStream_t stream) {
    const float* inputs = (const float*)d_in[0];   // [4096,5,1]
    const float* Wx     = (const float*)d_in[1];   // [1,4096]
    const float* R      = (const float*)d_in[2];   // [1024,4096]
    const float* bias   = (const float*)d_in[3];   // [4096]
    const float* w1     = (const float*)d_in[4];   // [1024,1]
    const float* b1     = (const float*)d_in[5];
    const float* w2     = (const float*)d_in[6];
    const float* b2     = (const float*)d_in[7];
    float* out = (float*)d_out;

    char* ws = (char*)d_ws;
    const size_t RP_BYTES = (size_t)32 * 131072 * 2;          // 8 MB
    const size_t H_BYTES  = (size_t)B_SZ * U_SZ * 2;          // 8 MB
    const size_t C_BYTES  = (size_t)B_SZ * U_SZ * 4;          // 16 MB
    bf16_t* Rp   = (bf16_t*)ws;                ws += RP_BYTES;
    bf16_t* h0   = (bf16_t*)ws;                ws += H_BYTES;
    bf16_t* h1   = (bf16_t*)ws;                ws += H_BYTES;
    float*  cbuf = (float*)ws;                 ws += C_BYTES;
    float*  praw = (float*)ws;                 ws += 3 * B_SZ * 4;
    bf16_t* hb[2] = {h0, h1};

    hipMemsetAsync(h0, 0, H_BYTES, stream);
    hipMemsetAsync(cbuf, 0, C_BYTES, stream);
    hipMemsetAsync(praw, 0, 3 * B_SZ * 4, stream);

    pack_R<<<16384, 256, 0, stream>>>(R, Rp);

    dim3 grid(16, 32);   // p fastest -> B panels pinned per XCD
    int cur = 0;
    for (int t = 0; t < STEPS; ++t) {
        lstm_step<<<grid, 256, 0, stream>>>(hb[cur], hb[1 - cur], cbuf, Rp,
                                            Wx, bias, w1, b1, w2, b2,
                                            inputs, praw, out, t);
        cur ^= 1;
    }
    pred_final<<<16, 256, 0, stream>>>(praw, b1, w2, b2, out);
}